// Round 2
// baseline (883.565 us; speedup 1.0000x reference)
//
#include <hip/hip_runtime.h>
#include <hip/hip_bf16.h>

#define N_NODES 12288
#define N_EDGES 393216
#define F_DIMC  512
#define H_DIMC  64

typedef __bf16 bf16x8 __attribute__((ext_vector_type(8)));
typedef float  floatx4 __attribute__((ext_vector_type(4)));

// ---------------- CSR build ----------------
__global__ void count_kernel(const int* __restrict__ dst, int* __restrict__ counts) {
    int e = blockIdx.x * 256 + threadIdx.x;
    if (e < N_EDGES) atomicAdd(&counts[dst[e]], 1);
}

__global__ __launch_bounds__(1024) void scan_kernel(const int* __restrict__ counts,
                                                    int* __restrict__ offs,
                                                    int* __restrict__ cursor) {
    __shared__ int part[1024];
    int t = threadIdx.x;
    int base = t * 12;                 // 12288 = 1024 * 12
    int local[12];
    int sum = 0;
#pragma unroll
    for (int i = 0; i < 12; i++) { local[i] = counts[base + i]; sum += local[i]; }
    part[t] = sum;
    __syncthreads();
    for (int off = 1; off < 1024; off <<= 1) {
        int v = (t >= off) ? part[t - off] : 0;
        __syncthreads();
        part[t] += v;
        __syncthreads();
    }
    int prefix = part[t] - sum;        // exclusive
#pragma unroll
    for (int i = 0; i < 12; i++) {
        offs[base + i] = prefix;
        cursor[base + i] = prefix;
        prefix += local[i];
    }
    if (t == 1023) offs[N_NODES] = N_EDGES;
}

__global__ void fill_kernel(const int* __restrict__ src, const int* __restrict__ dst,
                            int* __restrict__ cursor, int* __restrict__ csr) {
    int e = blockIdx.x * 256 + threadIdx.x;
    if (e < N_EDGES) {
        int d = dst[e];
        int pos = atomicAdd(&cursor[d], 1);
        csr[pos] = src[e];
    }
}

// ---------------- fp32 GEMMs ----------------
// [N,512] @ [512,64] -> [N,64]
__global__ __launch_bounds__(256) void gemm_k512(const float* __restrict__ X,
                                                 const float* __restrict__ W,
                                                 float* __restrict__ out) {
    int c = threadIdx.x & 63, rq = threadIdx.x >> 6;
    int row0 = blockIdx.x * 32 + rq * 8;
    float acc[8] = {0.f, 0.f, 0.f, 0.f, 0.f, 0.f, 0.f, 0.f};
    for (int k = 0; k < F_DIMC; k += 4) {
        float w0 = W[(k + 0) * H_DIMC + c];
        float w1 = W[(k + 1) * H_DIMC + c];
        float w2 = W[(k + 2) * H_DIMC + c];
        float w3 = W[(k + 3) * H_DIMC + c];
#pragma unroll
        for (int r = 0; r < 8; r++) {
            float4 hv = *(const float4*)(X + (size_t)(row0 + r) * F_DIMC + k);
            acc[r] += hv.x * w0 + hv.y * w1 + hv.z * w2 + hv.w * w3;
        }
    }
#pragma unroll
    for (int r = 0; r < 8; r++) out[(row0 + r) * H_DIMC + c] = acc[r];
}

// [N,64] @ [64,64] -> [N,64]   (W staged in LDS)
__global__ __launch_bounds__(256) void gemm_k64(const float* __restrict__ X,
                                                const float* __restrict__ W,
                                                float* __restrict__ out) {
    __shared__ float Wl[H_DIMC * H_DIMC];
    for (int i = threadIdx.x; i < H_DIMC * H_DIMC; i += 256) Wl[i] = W[i];
    __syncthreads();
    int c = threadIdx.x & 63, rq = threadIdx.x >> 6;
    int row0 = blockIdx.x * 32 + rq * 8;
    float acc[8] = {0.f, 0.f, 0.f, 0.f, 0.f, 0.f, 0.f, 0.f};
    for (int k = 0; k < H_DIMC; k += 4) {
        float w0 = Wl[(k + 0) * 64 + c];
        float w1 = Wl[(k + 1) * 64 + c];
        float w2 = Wl[(k + 2) * 64 + c];
        float w3 = Wl[(k + 3) * 64 + c];
#pragma unroll
        for (int r = 0; r < 8; r++) {
            float4 xv = *(const float4*)(X + (row0 + r) * 64 + k);
            acc[r] += xv.x * w0 + xv.y * w1 + xv.z * w2 + xv.w * w3;
        }
    }
#pragma unroll
    for (int r = 0; r < 8; r++) out[(row0 + r) * 64 + c] = acc[r];
}

// [N,64] @ [64,64] x2 (shared X reads, both W in LDS) -> two outputs
__global__ __launch_bounds__(256) void gemm_k64_dual(const float* __restrict__ X,
                                                     const float* __restrict__ Wa,
                                                     const float* __restrict__ Wb,
                                                     float* __restrict__ outA,
                                                     float* __restrict__ outB) {
    __shared__ float Wl[2][H_DIMC * H_DIMC];
    for (int i = threadIdx.x; i < H_DIMC * H_DIMC; i += 256) {
        Wl[0][i] = Wa[i];
        Wl[1][i] = Wb[i];
    }
    __syncthreads();
    int c = threadIdx.x & 63, rq = threadIdx.x >> 6;
    int row0 = blockIdx.x * 32 + rq * 8;
    float accA[8] = {0.f, 0.f, 0.f, 0.f, 0.f, 0.f, 0.f, 0.f};
    float accB[8] = {0.f, 0.f, 0.f, 0.f, 0.f, 0.f, 0.f, 0.f};
    for (int k = 0; k < H_DIMC; k += 4) {
        float wa0 = Wl[0][(k + 0) * 64 + c], wa1 = Wl[0][(k + 1) * 64 + c];
        float wa2 = Wl[0][(k + 2) * 64 + c], wa3 = Wl[0][(k + 3) * 64 + c];
        float wb0 = Wl[1][(k + 0) * 64 + c], wb1 = Wl[1][(k + 1) * 64 + c];
        float wb2 = Wl[1][(k + 2) * 64 + c], wb3 = Wl[1][(k + 3) * 64 + c];
#pragma unroll
        for (int r = 0; r < 8; r++) {
            float4 xv = *(const float4*)(X + (row0 + r) * 64 + k);
            accA[r] += xv.x * wa0 + xv.y * wa1 + xv.z * wa2 + xv.w * wa3;
            accB[r] += xv.x * wb0 + xv.y * wb1 + xv.z * wb2 + xv.w * wb3;
        }
    }
#pragma unroll
    for (int r = 0; r < 8; r++) {
        outA[(row0 + r) * 64 + c] = accA[r];
        outB[(row0 + r) * 64 + c] = accB[r];
    }
}

// [N,64] @ [64,512] + bias, relu -> [N,512]  (nontemporal out)
__global__ __launch_bounds__(256) void gemm_xhat(const float* __restrict__ A,
                                                 const float* __restrict__ W,
                                                 const float* __restrict__ bias,
                                                 float* __restrict__ out) {
    int c0 = threadIdx.x, c1 = threadIdx.x + 256;
    int row0 = blockIdx.x * 8;
    float acc0[8] = {0.f, 0.f, 0.f, 0.f, 0.f, 0.f, 0.f, 0.f};
    float acc1[8] = {0.f, 0.f, 0.f, 0.f, 0.f, 0.f, 0.f, 0.f};
    for (int k = 0; k < 64; k += 4) {
        float w00 = W[(k + 0) * 512 + c0], w01 = W[(k + 1) * 512 + c0];
        float w02 = W[(k + 2) * 512 + c0], w03 = W[(k + 3) * 512 + c0];
        float w10 = W[(k + 0) * 512 + c1], w11 = W[(k + 1) * 512 + c1];
        float w12 = W[(k + 2) * 512 + c1], w13 = W[(k + 3) * 512 + c1];
#pragma unroll
        for (int r = 0; r < 8; r++) {
            float4 av = *(const float4*)(A + (row0 + r) * 64 + k);
            acc0[r] += av.x * w00 + av.y * w01 + av.z * w02 + av.w * w03;
            acc1[r] += av.x * w10 + av.y * w11 + av.z * w12 + av.w * w13;
        }
    }
    float b0 = bias[c0], b1 = bias[c1];
#pragma unroll
    for (int r = 0; r < 8; r++) {
        __builtin_nontemporal_store(fmaxf(acc0[r] + b0, 0.f),
                                    out + (size_t)(row0 + r) * 512 + c0);
        __builtin_nontemporal_store(fmaxf(acc1[r] + b1, 0.f),
                                    out + (size_t)(row0 + r) * 512 + c1);
    }
}

// ---------------- aggregation (CSR gather-sum) ----------------
// mode 0: plain fp32 out; mode 1: bias+relu fp32 out
__global__ __launch_bounds__(256) void agg_kernel(const float* __restrict__ m,
                                                  const int* __restrict__ offs,
                                                  const int* __restrict__ csr,
                                                  const float* __restrict__ bias,
                                                  int mode,
                                                  float* __restrict__ out) {
    int node = (blockIdx.x * 256 + threadIdx.x) >> 6;  // one wave per node
    int lane = threadIdx.x & 63;                       // lane = feature
    int e = offs[node], end = offs[node + 1];
    float acc = 0.f;
    for (; e + 4 <= end; e += 4) {
        int s0 = csr[e + 0], s1 = csr[e + 1], s2 = csr[e + 2], s3 = csr[e + 3];
        float v0 = m[s0 * 64 + lane];
        float v1 = m[s1 * 64 + lane];
        float v2 = m[s2 * 64 + lane];
        float v3 = m[s3 * 64 + lane];
        acc += (v0 + v1) + (v2 + v3);
    }
    for (; e < end; e++) acc += m[csr[e] * 64 + lane];
    if (mode != 0) { acc += bias[lane]; acc = fmaxf(acc, 0.f); }
    out[node * 64 + lane] = acc;
}

// dual gather: xa (fp32, bias+relu) and s (bf16, bias+relu) in one CSR pass
__global__ __launch_bounds__(256) void agg_dual_kernel(const float* __restrict__ ma,
                                                       const float* __restrict__ ms,
                                                       const int* __restrict__ offs,
                                                       const int* __restrict__ csr,
                                                       const float* __restrict__ ba,
                                                       const float* __restrict__ bsv,
                                                       float* __restrict__ outa,
                                                       __hip_bfloat16* __restrict__ outs) {
    int node = (blockIdx.x * 256 + threadIdx.x) >> 6;
    int lane = threadIdx.x & 63;
    int e = offs[node], end = offs[node + 1];
    float acca = 0.f, accs = 0.f;
    for (; e + 4 <= end; e += 4) {
        int s0 = csr[e + 0], s1 = csr[e + 1], s2 = csr[e + 2], s3 = csr[e + 3];
        float a0 = ma[s0 * 64 + lane], a1 = ma[s1 * 64 + lane];
        float a2 = ma[s2 * 64 + lane], a3 = ma[s3 * 64 + lane];
        float c0 = ms[s0 * 64 + lane], c1 = ms[s1 * 64 + lane];
        float c2 = ms[s2 * 64 + lane], c3 = ms[s3 * 64 + lane];
        acca += (a0 + a1) + (a2 + a3);
        accs += (c0 + c1) + (c2 + c3);
    }
    for (; e < end; e++) {
        int sIdx = csr[e];
        acca += ma[sIdx * 64 + lane];
        accs += ms[sIdx * 64 + lane];
    }
    acca = fmaxf(acca + ba[lane], 0.f);
    accs = fmaxf(accs + bsv[lane], 0.f);
    outa[node * 64 + lane] = acca;
    outs[node * 64 + lane] = __float2bfloat16(accs);
}

// ---------------- S = s @ s.T via bf16 MFMA, fp32 out ----------------
// LDS-staged epilogue: coalesced nontemporal dwordx4 stores.
__global__ __launch_bounds__(256) void sst_kernel(const __hip_bfloat16* __restrict__ sbh,
                                                  float* __restrict__ out) {
    const __bf16* sb = (const __bf16*)sbh;
    __shared__ float tile[64][132];    // 33.8 KB, +4 pad -> write-phase conflicts are 2-way (free)
    int wave = threadIdx.x >> 6;
    int lane = threadIdx.x & 63;
    int lr = lane & 15, quad = lane >> 4;
    int bi0 = blockIdx.y * 128;
    int bj0 = blockIdx.x * 128;
    int i0 = bi0 + (wave >> 1) * 64;   // output rows this wave
    int j0 = bj0 + (wave & 1) * 64;    // output cols this wave

    floatx4 acc[4][4];
#pragma unroll
    for (int r = 0; r < 4; r++)
#pragma unroll
        for (int c = 0; c < 4; c++) {
            acc[r][c][0] = 0.f; acc[r][c][1] = 0.f; acc[r][c][2] = 0.f; acc[r][c][3] = 0.f;
        }

#pragma unroll
    for (int ks = 0; ks < 64; ks += 32) {
        bf16x8 a[4], b[4];
#pragma unroll
        for (int t = 0; t < 4; t++)
            a[t] = *(const bf16x8*)(sb + (size_t)(i0 + t * 16 + lr) * 64 + ks + quad * 8);
#pragma unroll
        for (int t = 0; t < 4; t++)
            b[t] = *(const bf16x8*)(sb + (size_t)(j0 + t * 16 + lr) * 64 + ks + quad * 8);
#pragma unroll
        for (int r = 0; r < 4; r++)
#pragma unroll
            for (int c = 0; c < 4; c++)
                acc[r][c] = __builtin_amdgcn_mfma_f32_16x16x32_bf16(a[r], b[c], acc[r][c], 0, 0, 0);
    }

    // Two passes: stage 64 rows x 128 cols in LDS, then coalesced stores.
    int row_base = quad * 4;                 // within this wave's 64-row band
    int col_base = (wave & 1) * 64 + lr;     // within the 128-col tile
    int tr = threadIdx.x >> 5;               // 0..7: store-phase row within group
    int c4 = (threadIdx.x & 31) * 4;         // store-phase col (floats)
#pragma unroll
    for (int p = 0; p < 2; p++) {
        if ((wave >> 1) == p) {
#pragma unroll
            for (int r = 0; r < 4; r++)
#pragma unroll
                for (int c = 0; c < 4; c++) {
#pragma unroll
                    for (int g = 0; g < 4; g++)
                        tile[row_base + r * 16 + g][col_base + c * 16] = acc[r][c][g];
                }
        }
        __syncthreads();
#pragma unroll
        for (int i = 0; i < 8; i++) {
            int row = i * 8 + tr;            // 0..63
            floatx4 v = *(const floatx4*)&tile[row][c4];
            __builtin_nontemporal_store(
                v, (floatx4*)(out + (size_t)(bi0 + p * 64 + row) * N_NODES + bj0 + c4));
        }
        __syncthreads();
    }
}

extern "C" void kernel_launch(void* const* d_in, const int* in_sizes, int n_in,
                              void* d_out, int out_size, void* d_ws, size_t ws_size,
                              hipStream_t stream) {
    const float* h   = (const float*)d_in[0];
    const int*   ei  = (const int*)d_in[1];
    const int*   esrc = ei;
    const int*   edst = ei + N_EDGES;
    const float* W1  = (const float*)d_in[2];
    const float* b1  = (const float*)d_in[3];
    const float* W2  = (const float*)d_in[4];
    const float* b2  = (const float*)d_in[5];
    const float* Wa1 = (const float*)d_in[6];
    const float* ba1 = (const float*)d_in[7];
    const float* Wa2 = (const float*)d_in[8];
    const float* ba2 = (const float*)d_in[9];
    const float* Wsm = (const float*)d_in[10];
    const float* bs  = (const float*)d_in[11];
    float* out = (float*)d_out;

    char* ws = (char*)d_ws;
    const size_t NF = (size_t)N_NODES * H_DIMC;   // 786432
    float* buf_m   = (float*)ws; ws += NF * 4;
    float* buf_x   = (float*)ws; ws += NF * 4;    // reused as second dual-GEMM output
    float* buf_x2  = (float*)ws; ws += NF * 4;
    float* buf_xa  = (float*)ws; ws += NF * 4;
    float* buf_agg = (float*)ws; ws += NF * 4;
    int* counts = (int*)ws; ws += (size_t)N_NODES * 4;
    int* offs   = (int*)ws; ws += (size_t)(N_NODES + 4) * 4;
    int* cursor = (int*)ws; ws += (size_t)N_NODES * 4;
    int* csr    = (int*)ws; ws += (size_t)N_EDGES * 4;
    __hip_bfloat16* sb = (__hip_bfloat16*)ws; ws += NF * 2;

    // CSR build (same graph reused by all aggregations)
    hipMemsetAsync(counts, 0, (size_t)N_NODES * 4, stream);
    count_kernel<<<N_EDGES / 256, 256, 0, stream>>>(edst, counts);
    scan_kernel<<<1, 1024, 0, stream>>>(counts, offs, cursor);
    fill_kernel<<<N_EDGES / 256, 256, 0, stream>>>(esrc, edst, cursor, csr);

    // encoder layer 1: x = relu(A·(h@W1) + b1)
    gemm_k512<<<N_NODES / 32, 256, 0, stream>>>(h, W1, buf_m);
    agg_kernel<<<N_NODES / 4, 256, 0, stream>>>(buf_m, offs, csr, b1, 1, buf_x);
    // encoder layer 2: x2 = relu(A·(x@W2) + b2)
    gemm_k64<<<N_NODES / 32, 256, 0, stream>>>(buf_x, W2, buf_m);
    agg_kernel<<<N_NODES / 4, 256, 0, stream>>>(buf_m, offs, csr, b2, 1, buf_x2);
    // fused: attribute decoder layer 1 + structure decoder GCN (both consume x2)
    //   buf_m = x2@Wa1, buf_x = x2@Ws  (buf_x dead after layer 2)
    gemm_k64_dual<<<N_NODES / 32, 256, 0, stream>>>(buf_x2, Wa1, Wsm, buf_m, buf_x);
    //   xa = relu(A·buf_m + ba1) fp32; s = relu(A·buf_x + bs) bf16
    agg_dual_kernel<<<N_NODES / 4, 256, 0, stream>>>(buf_m, buf_x, offs, csr,
                                                     ba1, bs, buf_xa, sb);
    // attribute decoder layer 2 (linearity reorder): x_hat = relu((A·xa)@Wa2 + ba2)
    agg_kernel<<<N_NODES / 4, 256, 0, stream>>>(buf_xa, offs, csr, ba2, 0, buf_agg);
    gemm_xhat<<<N_NODES / 8, 256, 0, stream>>>(buf_agg, Wa2, ba2,
                                               out + (size_t)N_NODES * N_NODES);
    // structure decode: S = s@s.T
    dim3 g(N_NODES / 128, N_NODES / 128);
    sst_kernel<<<g, 256, 0, stream>>>(sb, out);
}

// Round 3
// 878.067 us; speedup vs baseline: 1.0063x; 1.0063x over previous
//
#include <hip/hip_runtime.h>
#include <hip/hip_bf16.h>

#define N_NODES 12288
#define N_EDGES 393216
#define F_DIMC  512
#define H_DIMC  64

typedef __bf16 bf16x8 __attribute__((ext_vector_type(8)));
typedef float  floatx4 __attribute__((ext_vector_type(4)));

// ---------------- CSR build ----------------
__global__ void count_kernel(const int* __restrict__ dst, int* __restrict__ counts) {
    int e = blockIdx.x * 256 + threadIdx.x;
    if (e < N_EDGES) atomicAdd(&counts[dst[e]], 1);
}

__global__ __launch_bounds__(1024) void scan_kernel(const int* __restrict__ counts,
                                                    int* __restrict__ offs,
                                                    int* __restrict__ cursor) {
    __shared__ int part[1024];
    int t = threadIdx.x;
    int base = t * 12;                 // 12288 = 1024 * 12
    int local[12];
    int sum = 0;
#pragma unroll
    for (int i = 0; i < 12; i++) { local[i] = counts[base + i]; sum += local[i]; }
    part[t] = sum;
    __syncthreads();
    for (int off = 1; off < 1024; off <<= 1) {
        int v = (t >= off) ? part[t - off] : 0;
        __syncthreads();
        part[t] += v;
        __syncthreads();
    }
    int prefix = part[t] - sum;        // exclusive
#pragma unroll
    for (int i = 0; i < 12; i++) {
        offs[base + i] = prefix;
        cursor[base + i] = prefix;
        prefix += local[i];
    }
    if (t == 1023) offs[N_NODES] = N_EDGES;
}

__global__ void fill_kernel(const int* __restrict__ src, const int* __restrict__ dst,
                            int* __restrict__ cursor, int* __restrict__ csr) {
    int e = blockIdx.x * 256 + threadIdx.x;
    if (e < N_EDGES) {
        int d = dst[e];
        int pos = atomicAdd(&cursor[d], 1);
        csr[pos] = src[e];
    }
}

// ---------------- fp32 GEMMs ----------------
// [N,512] @ [512,64] -> [N,64]
__global__ __launch_bounds__(256) void gemm_k512(const float* __restrict__ X,
                                                 const float* __restrict__ W,
                                                 float* __restrict__ out) {
    int c = threadIdx.x & 63, rq = threadIdx.x >> 6;
    int row0 = blockIdx.x * 32 + rq * 8;
    float acc[8] = {0.f, 0.f, 0.f, 0.f, 0.f, 0.f, 0.f, 0.f};
    for (int k = 0; k < F_DIMC; k += 4) {
        float w0 = W[(k + 0) * H_DIMC + c];
        float w1 = W[(k + 1) * H_DIMC + c];
        float w2 = W[(k + 2) * H_DIMC + c];
        float w3 = W[(k + 3) * H_DIMC + c];
#pragma unroll
        for (int r = 0; r < 8; r++) {
            float4 hv = *(const float4*)(X + (size_t)(row0 + r) * F_DIMC + k);
            acc[r] += hv.x * w0 + hv.y * w1 + hv.z * w2 + hv.w * w3;
        }
    }
#pragma unroll
    for (int r = 0; r < 8; r++) out[(row0 + r) * H_DIMC + c] = acc[r];
}

// [N,64] @ [64,64] -> [N,64]   (W staged in LDS)
__global__ __launch_bounds__(256) void gemm_k64(const float* __restrict__ X,
                                                const float* __restrict__ W,
                                                float* __restrict__ out) {
    __shared__ float Wl[H_DIMC * H_DIMC];
    for (int i = threadIdx.x; i < H_DIMC * H_DIMC; i += 256) Wl[i] = W[i];
    __syncthreads();
    int c = threadIdx.x & 63, rq = threadIdx.x >> 6;
    int row0 = blockIdx.x * 32 + rq * 8;
    float acc[8] = {0.f, 0.f, 0.f, 0.f, 0.f, 0.f, 0.f, 0.f};
    for (int k = 0; k < H_DIMC; k += 4) {
        float w0 = Wl[(k + 0) * 64 + c];
        float w1 = Wl[(k + 1) * 64 + c];
        float w2 = Wl[(k + 2) * 64 + c];
        float w3 = Wl[(k + 3) * 64 + c];
#pragma unroll
        for (int r = 0; r < 8; r++) {
            float4 xv = *(const float4*)(X + (row0 + r) * 64 + k);
            acc[r] += xv.x * w0 + xv.y * w1 + xv.z * w2 + xv.w * w3;
        }
    }
#pragma unroll
    for (int r = 0; r < 8; r++) out[(row0 + r) * 64 + c] = acc[r];
}

// [N,64] @ [64,64] x2 (shared X reads, both W in LDS) -> two outputs
__global__ __launch_bounds__(256) void gemm_k64_dual(const float* __restrict__ X,
                                                     const float* __restrict__ Wa,
                                                     const float* __restrict__ Wb,
                                                     float* __restrict__ outA,
                                                     float* __restrict__ outB) {
    __shared__ float Wl[2][H_DIMC * H_DIMC];
    for (int i = threadIdx.x; i < H_DIMC * H_DIMC; i += 256) {
        Wl[0][i] = Wa[i];
        Wl[1][i] = Wb[i];
    }
    __syncthreads();
    int c = threadIdx.x & 63, rq = threadIdx.x >> 6;
    int row0 = blockIdx.x * 32 + rq * 8;
    float accA[8] = {0.f, 0.f, 0.f, 0.f, 0.f, 0.f, 0.f, 0.f};
    float accB[8] = {0.f, 0.f, 0.f, 0.f, 0.f, 0.f, 0.f, 0.f};
    for (int k = 0; k < H_DIMC; k += 4) {
        float wa0 = Wl[0][(k + 0) * 64 + c], wa1 = Wl[0][(k + 1) * 64 + c];
        float wa2 = Wl[0][(k + 2) * 64 + c], wa3 = Wl[0][(k + 3) * 64 + c];
        float wb0 = Wl[1][(k + 0) * 64 + c], wb1 = Wl[1][(k + 1) * 64 + c];
        float wb2 = Wl[1][(k + 2) * 64 + c], wb3 = Wl[1][(k + 3) * 64 + c];
#pragma unroll
        for (int r = 0; r < 8; r++) {
            float4 xv = *(const float4*)(X + (row0 + r) * 64 + k);
            accA[r] += xv.x * wa0 + xv.y * wa1 + xv.z * wa2 + xv.w * wa3;
            accB[r] += xv.x * wb0 + xv.y * wb1 + xv.z * wb2 + xv.w * wb3;
        }
    }
#pragma unroll
    for (int r = 0; r < 8; r++) {
        outA[(row0 + r) * 64 + c] = accA[r];
        outB[(row0 + r) * 64 + c] = accB[r];
    }
}

// ---------------- aggregation (CSR gather-sum) ----------------
// bias+relu fp32 out; 8-wide gather unroll for memory-level parallelism
__global__ __launch_bounds__(256) void agg_kernel(const float* __restrict__ m,
                                                  const int* __restrict__ offs,
                                                  const int* __restrict__ csr,
                                                  const float* __restrict__ bias,
                                                  float* __restrict__ out) {
    int node = (blockIdx.x * 256 + threadIdx.x) >> 6;  // one wave per node
    int lane = threadIdx.x & 63;                       // lane = feature
    int e = offs[node], end = offs[node + 1];
    float acc = 0.f;
    for (; e + 8 <= end; e += 8) {
        int s0 = csr[e + 0], s1 = csr[e + 1], s2 = csr[e + 2], s3 = csr[e + 3];
        int s4 = csr[e + 4], s5 = csr[e + 5], s6 = csr[e + 6], s7 = csr[e + 7];
        float v0 = m[s0 * 64 + lane], v1 = m[s1 * 64 + lane];
        float v2 = m[s2 * 64 + lane], v3 = m[s3 * 64 + lane];
        float v4 = m[s4 * 64 + lane], v5 = m[s5 * 64 + lane];
        float v6 = m[s6 * 64 + lane], v7 = m[s7 * 64 + lane];
        acc += ((v0 + v1) + (v2 + v3)) + ((v4 + v5) + (v6 + v7));
    }
    for (; e < end; e++) acc += m[csr[e] * 64 + lane];
    acc += bias[lane];
    acc = fmaxf(acc, 0.f);
    out[node * 64 + lane] = acc;
}

// dual gather: xa (fp32, bias+relu) and s (bf16, bias+relu) in one CSR pass
__global__ __launch_bounds__(256) void agg_dual_kernel(const float* __restrict__ ma,
                                                       const float* __restrict__ ms,
                                                       const int* __restrict__ offs,
                                                       const int* __restrict__ csr,
                                                       const float* __restrict__ ba,
                                                       const float* __restrict__ bsv,
                                                       float* __restrict__ outa,
                                                       __hip_bfloat16* __restrict__ outs) {
    int node = (blockIdx.x * 256 + threadIdx.x) >> 6;
    int lane = threadIdx.x & 63;
    int e = offs[node], end = offs[node + 1];
    float acca = 0.f, accs = 0.f;
    for (; e + 8 <= end; e += 8) {
        int s0 = csr[e + 0], s1 = csr[e + 1], s2 = csr[e + 2], s3 = csr[e + 3];
        int s4 = csr[e + 4], s5 = csr[e + 5], s6 = csr[e + 6], s7 = csr[e + 7];
        float a0 = ma[s0 * 64 + lane], a1 = ma[s1 * 64 + lane];
        float a2 = ma[s2 * 64 + lane], a3 = ma[s3 * 64 + lane];
        float a4 = ma[s4 * 64 + lane], a5 = ma[s5 * 64 + lane];
        float a6 = ma[s6 * 64 + lane], a7 = ma[s7 * 64 + lane];
        float c0 = ms[s0 * 64 + lane], c1 = ms[s1 * 64 + lane];
        float c2 = ms[s2 * 64 + lane], c3 = ms[s3 * 64 + lane];
        float c4 = ms[s4 * 64 + lane], c5 = ms[s5 * 64 + lane];
        float c6 = ms[s6 * 64 + lane], c7 = ms[s7 * 64 + lane];
        acca += ((a0 + a1) + (a2 + a3)) + ((a4 + a5) + (a6 + a7));
        accs += ((c0 + c1) + (c2 + c3)) + ((c4 + c5) + (c6 + c7));
    }
    for (; e < end; e++) {
        int sIdx = csr[e];
        acca += ma[sIdx * 64 + lane];
        accs += ms[sIdx * 64 + lane];
    }
    acca = fmaxf(acca + ba[lane], 0.f);
    accs = fmaxf(accs + bsv[lane], 0.f);
    outa[node * 64 + lane] = acca;
    outs[node * 64 + lane] = __float2bfloat16(accs);
}

// ---------------- fused: agg(no bias) -> [8,64] in LDS -> @[64,512]+bias,relu ----------------
// x_hat = relu((A·xa)@Wa2 + ba2). Block = 8 nodes; 8 waves gather, then 512 threads GEMM.
__global__ __launch_bounds__(512) void agg_gemm_xhat(const float* __restrict__ xa,
                                                     const int* __restrict__ offs,
                                                     const int* __restrict__ csr,
                                                     const float* __restrict__ W,
                                                     const float* __restrict__ bias,
                                                     float* __restrict__ out) {
    __shared__ float Al[8][64];
    int node0 = blockIdx.x * 8;
    {
        int w = threadIdx.x >> 6;          // 0..7: wave -> node
        int lane = threadIdx.x & 63;       // feature
        int node = node0 + w;
        int e = offs[node], end = offs[node + 1];
        float acc = 0.f;
        for (; e + 8 <= end; e += 8) {
            int s0 = csr[e + 0], s1 = csr[e + 1], s2 = csr[e + 2], s3 = csr[e + 3];
            int s4 = csr[e + 4], s5 = csr[e + 5], s6 = csr[e + 6], s7 = csr[e + 7];
            float v0 = xa[s0 * 64 + lane], v1 = xa[s1 * 64 + lane];
            float v2 = xa[s2 * 64 + lane], v3 = xa[s3 * 64 + lane];
            float v4 = xa[s4 * 64 + lane], v5 = xa[s5 * 64 + lane];
            float v6 = xa[s6 * 64 + lane], v7 = xa[s7 * 64 + lane];
            acc += ((v0 + v1) + (v2 + v3)) + ((v4 + v5) + (v6 + v7));
        }
        for (; e < end; e++) acc += xa[csr[e] * 64 + lane];
        Al[w][lane] = acc;
    }
    __syncthreads();
    int c = threadIdx.x;                   // 0..511: output column
    float acc[8] = {0.f, 0.f, 0.f, 0.f, 0.f, 0.f, 0.f, 0.f};
    for (int k = 0; k < 64; k += 4) {
        float w0 = W[(k + 0) * 512 + c];
        float w1 = W[(k + 1) * 512 + c];
        float w2 = W[(k + 2) * 512 + c];
        float w3 = W[(k + 3) * 512 + c];
#pragma unroll
        for (int r = 0; r < 8; r++) {
            acc[r] += Al[r][k] * w0 + Al[r][k + 1] * w1 + Al[r][k + 2] * w2 + Al[r][k + 3] * w3;
        }
    }
    float b = bias[c];
#pragma unroll
    for (int r = 0; r < 8; r++) {
        __builtin_nontemporal_store(fmaxf(acc[r] + b, 0.f),
                                    out + (size_t)(node0 + r) * 512 + c);
    }
}

// ---------------- S = s @ s.T via bf16 MFMA, fp32 out ----------------
// LDS-staged epilogue: coalesced nontemporal dwordx4 stores.
__global__ __launch_bounds__(256) void sst_kernel(const __hip_bfloat16* __restrict__ sbh,
                                                  float* __restrict__ out) {
    const __bf16* sb = (const __bf16*)sbh;
    __shared__ float tile[64][132];    // 33.8 KB, +4 pad -> write-phase conflicts are 2-way (free)
    int wave = threadIdx.x >> 6;
    int lane = threadIdx.x & 63;
    int lr = lane & 15, quad = lane >> 4;
    int bi0 = blockIdx.y * 128;
    int bj0 = blockIdx.x * 128;
    int i0 = bi0 + (wave >> 1) * 64;   // output rows this wave
    int j0 = bj0 + (wave & 1) * 64;    // output cols this wave

    floatx4 acc[4][4];
#pragma unroll
    for (int r = 0; r < 4; r++)
#pragma unroll
        for (int c = 0; c < 4; c++) {
            acc[r][c][0] = 0.f; acc[r][c][1] = 0.f; acc[r][c][2] = 0.f; acc[r][c][3] = 0.f;
        }

#pragma unroll
    for (int ks = 0; ks < 64; ks += 32) {
        bf16x8 a[4], b[4];
#pragma unroll
        for (int t = 0; t < 4; t++)
            a[t] = *(const bf16x8*)(sb + (size_t)(i0 + t * 16 + lr) * 64 + ks + quad * 8);
#pragma unroll
        for (int t = 0; t < 4; t++)
            b[t] = *(const bf16x8*)(sb + (size_t)(j0 + t * 16 + lr) * 64 + ks + quad * 8);
#pragma unroll
        for (int r = 0; r < 4; r++)
#pragma unroll
            for (int c = 0; c < 4; c++)
                acc[r][c] = __builtin_amdgcn_mfma_f32_16x16x32_bf16(a[r], b[c], acc[r][c], 0, 0, 0);
    }

    // Two passes: stage 64 rows x 128 cols in LDS, then coalesced stores.
    int row_base = quad * 4;                 // within this wave's 64-row band
    int col_base = (wave & 1) * 64 + lr;     // within the 128-col tile
    int tr = threadIdx.x >> 5;               // 0..7: store-phase row within group
    int c4 = (threadIdx.x & 31) * 4;         // store-phase col (floats)
#pragma unroll
    for (int p = 0; p < 2; p++) {
        if ((wave >> 1) == p) {
#pragma unroll
            for (int r = 0; r < 4; r++)
#pragma unroll
                for (int c = 0; c < 4; c++) {
#pragma unroll
                    for (int g = 0; g < 4; g++)
                        tile[row_base + r * 16 + g][col_base + c * 16] = acc[r][c][g];
                }
        }
        __syncthreads();
#pragma unroll
        for (int i = 0; i < 8; i++) {
            int row = i * 8 + tr;            // 0..63
            floatx4 v = *(const floatx4*)&tile[row][c4];
            __builtin_nontemporal_store(
                v, (floatx4*)(out + (size_t)(bi0 + p * 64 + row) * N_NODES + bj0 + c4));
        }
        __syncthreads();
    }
}

extern "C" void kernel_launch(void* const* d_in, const int* in_sizes, int n_in,
                              void* d_out, int out_size, void* d_ws, size_t ws_size,
                              hipStream_t stream) {
    const float* h   = (const float*)d_in[0];
    const int*   ei  = (const int*)d_in[1];
    const int*   esrc = ei;
    const int*   edst = ei + N_EDGES;
    const float* W1  = (const float*)d_in[2];
    const float* b1  = (const float*)d_in[3];
    const float* W2  = (const float*)d_in[4];
    const float* b2  = (const float*)d_in[5];
    const float* Wa1 = (const float*)d_in[6];
    const float* ba1 = (const float*)d_in[7];
    const float* Wa2 = (const float*)d_in[8];
    const float* ba2 = (const float*)d_in[9];
    const float* Wsm = (const float*)d_in[10];
    const float* bs  = (const float*)d_in[11];
    float* out = (float*)d_out;

    char* ws = (char*)d_ws;
    const size_t NF = (size_t)N_NODES * H_DIMC;   // 786432
    float* buf_m   = (float*)ws; ws += NF * 4;
    float* buf_x   = (float*)ws; ws += NF * 4;    // reused as second dual-GEMM output
    float* buf_x2  = (float*)ws; ws += NF * 4;
    float* buf_xa  = (float*)ws; ws += NF * 4;
    int* counts = (int*)ws; ws += (size_t)N_NODES * 4;
    int* offs   = (int*)ws; ws += (size_t)(N_NODES + 4) * 4;
    int* cursor = (int*)ws; ws += (size_t)N_NODES * 4;
    int* csr    = (int*)ws; ws += (size_t)N_EDGES * 4;
    __hip_bfloat16* sb = (__hip_bfloat16*)ws; ws += NF * 2;

    // CSR build (same graph reused by all aggregations)
    hipMemsetAsync(counts, 0, (size_t)N_NODES * 4, stream);
    count_kernel<<<N_EDGES / 256, 256, 0, stream>>>(edst, counts);
    scan_kernel<<<1, 1024, 0, stream>>>(counts, offs, cursor);
    fill_kernel<<<N_EDGES / 256, 256, 0, stream>>>(esrc, edst, cursor, csr);

    // encoder layer 1: x = relu(A·(h@W1) + b1)
    gemm_k512<<<N_NODES / 32, 256, 0, stream>>>(h, W1, buf_m);
    agg_kernel<<<N_NODES / 4, 256, 0, stream>>>(buf_m, offs, csr, b1, buf_x);
    // encoder layer 2: x2 = relu(A·(x@W2) + b2)
    gemm_k64<<<N_NODES / 32, 256, 0, stream>>>(buf_x, W2, buf_m);
    agg_kernel<<<N_NODES / 4, 256, 0, stream>>>(buf_m, offs, csr, b2, buf_x2);
    // fused: attribute decoder layer 1 + structure decoder GCN (both consume x2)
    //   buf_m = x2@Wa1, buf_x = x2@Ws  (buf_x dead after layer 2)
    gemm_k64_dual<<<N_NODES / 32, 256, 0, stream>>>(buf_x2, Wa1, Wsm, buf_m, buf_x);
    //   xa = relu(A·buf_m + ba1) fp32; s = relu(A·buf_x + bs) bf16
    agg_dual_kernel<<<N_NODES / 4, 256, 0, stream>>>(buf_m, buf_x, offs, csr,
                                                     ba1, bs, buf_xa, sb);
    // attribute decoder layer 2 (linearity reorder, fused agg+GEMM):
    //   x_hat = relu((A·xa)@Wa2 + ba2)
    agg_gemm_xhat<<<N_NODES / 8, 512, 0, stream>>>(buf_xa, offs, csr, Wa2, ba2,
                                                   out + (size_t)N_NODES * N_NODES);
    // structure decode: S = s@s.T
    dim3 g(N_NODES / 128, N_NODES / 128);
    sst_kernel<<<g, 256, 0, stream>>>(sb, out);
}